// Round 1
// baseline (1147.879 us; speedup 1.0000x reference)
//
#include <hip/hip_runtime.h>
#include <hip/hip_bf16.h>
#include <cstdint>
#include <cstddef>

// MoE: N=8192 tokens, D=1024, H=2048, O=1024, E=8 experts, G=256 gate hidden, K=2
#define N_TOK 8192
#define D_IN  1024
#define H_DIM 2048
#define O_DIM 1024
#define E_NUM 8
#define G_DIM 256
#define MAXTILES 136            // ceil(16384/128) + 8 experts padding worst case
#define MAXROWS  (MAXTILES*128) // 17408

typedef __attribute__((ext_vector_type(8))) __bf16 bf16x8;
typedef __attribute__((ext_vector_type(4))) __bf16 bf16x4;
typedef __attribute__((ext_vector_type(4))) float floatx4;

#define GCAST(p) ((__attribute__((address_space(1))) void*)(void*)(p))
#define LCAST(p) ((__attribute__((address_space(3))) void*)(p))

// ---------------- cast x (fp32 -> bf16) ----------------
__global__ __launch_bounds__(256) void cast_x_kernel(const float* __restrict__ x,
                                                     __bf16* __restrict__ xb) {
  int i = (blockIdx.x * 256 + threadIdx.x) * 4;
  float4 v = *reinterpret_cast<const float4*>(x + i);
  bf16x4 o;
  o.x = (__bf16)v.x; o.y = (__bf16)v.y; o.z = (__bf16)v.z; o.w = (__bf16)v.w;
  *reinterpret_cast<bf16x4*>(xb + i) = o;
}

// ---------------- transpose+cast weights: W[e][k][n] fp32 -> Wt[e][n][k] bf16 ----------------
__global__ __launch_bounds__(256) void transpose_w_kernel(const float* __restrict__ src,
                                                          __bf16* __restrict__ dst,
                                                          int K, int N) {
  __shared__ float tl[32][33];
  int e = blockIdx.z;
  const float* s = src + (size_t)e * K * N;
  __bf16* d = dst + (size_t)e * K * N;
  int k0 = blockIdx.y * 32, n0 = blockIdx.x * 32;
  int t = threadIdx.x;
  int r = t >> 5, c = t & 31;
#pragma unroll
  for (int i = 0; i < 4; i++)
    tl[r + i * 8][c] = s[(size_t)(k0 + r + i * 8) * N + n0 + c];
  __syncthreads();
#pragma unroll
  for (int i = 0; i < 4; i++)
    d[(size_t)(n0 + r + i * 8) * K + k0 + c] = (__bf16)tl[c][r + i * 8];
}

// ---------------- gate layer 1 (fp32 GEMM 8192x256x1024 + bias + relu) ----------------
// 64x64 tile / block of 256 threads, 4x4 per thread, Bk=32. A stored transposed in LDS.
__global__ __launch_bounds__(256) void gate1_kernel(const float* __restrict__ x,
                                                    const float* __restrict__ Wg1,
                                                    const float* __restrict__ bg1,
                                                    float* __restrict__ g) {
  __shared__ float As[32][68]; // [k][m], stride 68 keeps float4 16B-aligned, conflict-light
  __shared__ float Bs[32][68]; // [k][n]
  int bn = blockIdx.x, bm = blockIdx.y;
  int t = threadIdx.x;
  int tm = t >> 4, tn = t & 15;
  float acc[4][4] = {};
  for (int k0 = 0; k0 < D_IN; k0 += 32) {
#pragma unroll
    for (int i = 0; i < 2; i++) {
      int idx = t + 256 * i;
      int row = idx >> 3, c4 = idx & 7;
      float4 v = *reinterpret_cast<const float4*>(
          x + (size_t)(bm * 64 + row) * D_IN + k0 + c4 * 4);
      As[c4 * 4 + 0][row] = v.x;
      As[c4 * 4 + 1][row] = v.y;
      As[c4 * 4 + 2][row] = v.z;
      As[c4 * 4 + 3][row] = v.w;
      int brow = idx >> 4, bc4 = idx & 15;
      float4 wv = *reinterpret_cast<const float4*>(
          Wg1 + (size_t)(k0 + brow) * G_DIM + bn * 64 + bc4 * 4);
      *reinterpret_cast<float4*>(&Bs[brow][bc4 * 4]) = wv;
    }
    __syncthreads();
#pragma unroll
    for (int k = 0; k < 32; k++) {
      float4 av = *reinterpret_cast<const float4*>(&As[k][tm * 4]);
      float4 bv = *reinterpret_cast<const float4*>(&Bs[k][tn * 4]);
      float a4[4] = {av.x, av.y, av.z, av.w};
      float b4[4] = {bv.x, bv.y, bv.z, bv.w};
#pragma unroll
      for (int r = 0; r < 4; r++)
#pragma unroll
        for (int c = 0; c < 4; c++) acc[r][c] = fmaf(a4[r], b4[c], acc[r][c]);
    }
    __syncthreads();
  }
  int gr = bm * 64 + tm * 4, gc = bn * 64 + tn * 4;
#pragma unroll
  for (int r = 0; r < 4; r++) {
    float4 o;
    o.x = fmaxf(acc[r][0] + bg1[gc + 0], 0.f);
    o.y = fmaxf(acc[r][1] + bg1[gc + 1], 0.f);
    o.z = fmaxf(acc[r][2] + bg1[gc + 2], 0.f);
    o.w = fmaxf(acc[r][3] + bg1[gc + 3], 0.f);
    *reinterpret_cast<float4*>(g + (size_t)(gr + r) * G_DIM + gc) = o;
  }
}

// ---------------- gate layer 2 + softmax/top2/renorm ----------------
__global__ __launch_bounds__(256) void gate2_kernel(const float* __restrict__ g,
                                                    const float* __restrict__ Wg2,
                                                    const float* __restrict__ bg2,
                                                    int* __restrict__ top_idx,
                                                    float* __restrict__ top_w,
                                                    int* __restrict__ counts) {
  __shared__ float lg[32][9];
  int t = threadIdx.x;
  int tl = t >> 3, e = t & 7;
  int n = blockIdx.x * 32 + tl;
  const float* gr = g + (size_t)n * G_DIM;
  float acc = bg2[e];
  for (int i = 0; i < G_DIM; i += 4) {
    float4 v = *reinterpret_cast<const float4*>(gr + i);
    acc += v.x * Wg2[(i + 0) * E_NUM + e];
    acc += v.y * Wg2[(i + 1) * E_NUM + e];
    acc += v.z * Wg2[(i + 2) * E_NUM + e];
    acc += v.w * Wg2[(i + 3) * E_NUM + e];
  }
  lg[tl][e] = acc;
  __syncthreads();
  if (e == 0) {
    float l[8];
#pragma unroll
    for (int i = 0; i < 8; i++) l[i] = lg[tl][i];
    int i0 = 0;
    for (int i = 1; i < 8; i++)
      if (l[i] > l[i0]) i0 = i;           // first-occurrence max (matches top_k tiebreak)
    int i1 = (i0 == 0) ? 1 : 0;
    for (int i = 0; i < 8; i++)
      if (i != i0 && l[i] > l[i1]) i1 = i;
    // renormalized top-2 weights: softmax denom cancels exactly
    float d = expf(l[i1] - l[i0]);
    float w0 = 1.f / (1.f + d);
    float w1 = d * w0;
    top_idx[n * 2 + 0] = i0;
    top_idx[n * 2 + 1] = i1;
    top_w[n * 2 + 0] = w0;
    top_w[n * 2 + 1] = w1;
    atomicAdd(&counts[i0], 1);
    atomicAdd(&counts[i1], 1);
  }
}

// ---------------- prefix/tiles/aux-loss (single tiny block) ----------------
__global__ void g3_kernel(const int* __restrict__ counts, int* __restrict__ cursors,
                          int* __restrict__ off_pad, int* __restrict__ ntiles,
                          int* __restrict__ tile_meta, float* __restrict__ out_tail) {
  if (threadIdx.x == 0) {
    int off = 0, nt = 0;
    float mse = 0.f;
    for (int e = 0; e < E_NUM; e++) {
      off_pad[e] = off;
      int c = counts[e];
      int tiles = (c + 127) >> 7;
      for (int i = 0; i < tiles; i++) {
        tile_meta[nt * 2 + 0] = e;
        tile_meta[nt * 2 + 1] = off + i * 128;
        nt++;
      }
      off += tiles << 7;
      cursors[e] = 0;
      float u = (float)c / (float)N_TOK;
      out_tail[1 + e] = u;
      float dd = u - 0.125f;
      mse += dd * dd;
    }
    *ntiles = nt;
    out_tail[0] = (mse / 8.0f) * 0.01f; // balance_loss
  }
}

// ---------------- init padded row slots to (token 0, weight 0) ----------------
__global__ __launch_bounds__(256) void init_rows_kernel(int* __restrict__ slot_token,
                                                        float* __restrict__ slot_w) {
  int s = blockIdx.x * 256 + threadIdx.x;
  slot_token[s] = 0;
  slot_w[s] = 0.f;
}

// ---------------- scatter tokens into per-expert segments ----------------
__global__ __launch_bounds__(256) void scatter_kernel(const int* __restrict__ top_idx,
                                                      const float* __restrict__ top_w,
                                                      const int* __restrict__ off_pad,
                                                      int* __restrict__ cursors,
                                                      int* __restrict__ slot_token,
                                                      float* __restrict__ slot_w) {
  int n = blockIdx.x * 256 + threadIdx.x;
#pragma unroll
  for (int k = 0; k < 2; k++) {
    int e = top_idx[n * 2 + k];
    int pos = atomicAdd(&cursors[e], 1);
    int s = off_pad[e] + pos;
    slot_token[s] = n;
    slot_w[s] = top_w[n * 2 + k];
  }
}

// ---------------- expert GEMM: 128x128 tile, bf16 MFMA 16x16x32, global_load_lds staging ----------------
// A: [rows][Kdim] bf16 (gathered rows of x_bf, or contiguous h rows)
// Wt: [E][Ndim][Kdim] bf16 (pre-transposed so B-frag k's are contiguous)
// mode 0: h_out = relu(acc+bias) as bf16; mode 1: atomicAdd(out[token], w*(acc+bias))
__global__ __launch_bounds__(256) void moe_gemm_kernel(
    const __bf16* __restrict__ A, int Astride, int gatherA,
    const __bf16* __restrict__ Wt, const float* __restrict__ bias,
    int Kdim, int Ndim,
    const int* __restrict__ tile_meta, const int* __restrict__ ntiles_p,
    const int* __restrict__ slot_token, const float* __restrict__ slot_w,
    __bf16* __restrict__ h_out, float* __restrict__ out_final, int finalMode) {
  int tile = blockIdx.y;
  if (tile >= *ntiles_p) return;
  __shared__ __bf16 As[128 * 32];
  __shared__ __bf16 Bs[128 * 32];
  int ex = tile_meta[tile * 2 + 0];
  int slot0 = tile_meta[tile * 2 + 1];
  int n0 = blockIdx.x * 128;
  int t = threadIdx.x, l = t & 63, w = t >> 6;

  // staging address setup: lane-slot g covers LDS bytes g*16 => row g>>2, k-chunk g&3
  size_t aoff[2], boff[2];
#pragma unroll
  for (int i = 0; i < 2; i++) {
    int gidx = (w * 2 + i) * 64 + l;
    int row = gidx >> 2, kch = gidx & 3;
    int sl = slot0 + row;
    long long rb = gatherA ? (long long)slot_token[sl] * Astride
                           : (long long)sl * Astride;
    aoff[i] = (size_t)rb + kch * 8;
    boff[i] = ((size_t)ex * Ndim + n0 + row) * (size_t)Kdim + kch * 8;
  }

  int wm = (w >> 1) * 64, wn = (w & 1) * 64;
  int lm = l & 15, lq = l >> 4;
  floatx4 acc[4][4] = {};

  for (int k0 = 0; k0 < Kdim; k0 += 32) {
#pragma unroll
    for (int i = 0; i < 2; i++) {
      __builtin_amdgcn_global_load_lds(GCAST(A + aoff[i] + k0),
                                       LCAST((char*)As + w * 2048 + i * 1024),
                                       16, 0, 0);
      __builtin_amdgcn_global_load_lds(GCAST(Wt + boff[i] + k0),
                                       LCAST((char*)Bs + w * 2048 + i * 1024),
                                       16, 0, 0);
    }
    __syncthreads();
    bf16x8 af[4], bfr[4];
#pragma unroll
    for (int i = 0; i < 4; i++)
      af[i] = *reinterpret_cast<const bf16x8*>(As + (wm + i * 16 + lm) * 32 + lq * 8);
#pragma unroll
    for (int j = 0; j < 4; j++)
      bfr[j] = *reinterpret_cast<const bf16x8*>(Bs + (wn + j * 16 + lm) * 32 + lq * 8);
#pragma unroll
    for (int i = 0; i < 4; i++)
#pragma unroll
      for (int j = 0; j < 4; j++)
        acc[i][j] = __builtin_amdgcn_mfma_f32_16x16x32_bf16(af[i], bfr[j], acc[i][j], 0, 0, 0);
    __syncthreads();
  }

  // epilogue: C/D layout col=lane&15, row=(lane>>4)*4+reg  [m89-verified]
  float bcol[4];
#pragma unroll
  for (int j = 0; j < 4; j++) bcol[j] = bias[(size_t)ex * Ndim + n0 + wn + j * 16 + lm];

  if (finalMode) {
#pragma unroll
    for (int i = 0; i < 4; i++) {
#pragma unroll
      for (int r = 0; r < 4; r++) {
        int sl = slot0 + wm + i * 16 + lq * 4 + r;
        int tok = slot_token[sl];
        float wgt = slot_w[sl];
        float* orow = out_final + (size_t)tok * Ndim + n0 + wn + lm;
#pragma unroll
        for (int j = 0; j < 4; j++) {
          float v = acc[i][j][r] + bcol[j];
          atomicAdd(orow + j * 16, wgt * v); // padded rows: wgt=0 -> adds 0
        }
      }
    }
  } else {
#pragma unroll
    for (int i = 0; i < 4; i++) {
#pragma unroll
      for (int r = 0; r < 4; r++) {
        int sl = slot0 + wm + i * 16 + lq * 4 + r;
        __bf16* hrow = h_out + (size_t)sl * Ndim + n0 + wn + lm;
#pragma unroll
        for (int j = 0; j < 4; j++) {
          float v = fmaxf(acc[i][j][r] + bcol[j], 0.f);
          hrow[j * 16] = (__bf16)v;
        }
      }
    }
  }
}

// ---------------- launch ----------------
extern "C" void kernel_launch(void* const* d_in, const int* in_sizes, int n_in,
                              void* d_out, int out_size, void* d_ws, size_t ws_size,
                              hipStream_t stream) {
  const float* x   = (const float*)d_in[0];
  const float* Wg1 = (const float*)d_in[1];
  const float* bg1 = (const float*)d_in[2];
  const float* Wg2 = (const float*)d_in[3];
  const float* bg2 = (const float*)d_in[4];
  const float* W1  = (const float*)d_in[5];
  const float* b1  = (const float*)d_in[6];
  const float* W2  = (const float*)d_in[7];
  const float* b2  = (const float*)d_in[8];
  const float* W3  = (const float*)d_in[9];
  const float* b3  = (const float*)d_in[10];
  float* out = (float*)d_out;

  char* ws = (char*)d_ws;
  __bf16* x_bf       = (__bf16*)(ws + 0);          // 16,777,216
  __bf16* W1t        = (__bf16*)(ws + 16777216);   // 33,554,432
  __bf16* W2t        = (__bf16*)(ws + 50331648);   // 67,108,864
  __bf16* W3t        = (__bf16*)(ws + 117440512);  // 33,554,432
  __bf16* h1         = (__bf16*)(ws + 150994944);  // 71,303,168
  __bf16* h2         = (__bf16*)(ws + 222298112);  // 71,303,168
  float*  gbuf       = (float*) (ws + 293601280);  // 8,388,608
  int*    top_idx    = (int*)   (ws + 301989888);  // 65,536
  float*  top_w      = (float*) (ws + 302055424);  // 65,536
  int*    slot_token = (int*)   (ws + 302120960);  // 69,632
  float*  slot_w     = (float*) (ws + 302190592);  // 69,632
  int*    meta       = (int*)   (ws + 302260224);
  int* counts    = meta;       // 8
  int* cursors   = meta + 8;   // 8
  int* off_pad   = meta + 16;  // 8
  int* ntiles    = meta + 24;  // 1
  int* tile_meta = meta + 32;  // 272
  float* out_tail = out + (size_t)N_TOK * O_DIM;   // [balance_loss, usage x8]

  hipMemsetAsync(d_out, 0, ((size_t)N_TOK * O_DIM + 9) * sizeof(float), stream);
  hipMemsetAsync(meta, 0, 64, stream); // zero counts+cursors

  cast_x_kernel<<<(N_TOK * D_IN) / 1024, 256, 0, stream>>>(x, x_bf);
  transpose_w_kernel<<<dim3(H_DIM / 32, D_IN / 32, E_NUM), 256, 0, stream>>>(W1, W1t, D_IN, H_DIM);
  transpose_w_kernel<<<dim3(H_DIM / 32, H_DIM / 32, E_NUM), 256, 0, stream>>>(W2, W2t, H_DIM, H_DIM);
  transpose_w_kernel<<<dim3(O_DIM / 32, H_DIM / 32, E_NUM), 256, 0, stream>>>(W3, W3t, H_DIM, O_DIM);

  gate1_kernel<<<dim3(G_DIM / 64, N_TOK / 64), 256, 0, stream>>>(x, Wg1, bg1, gbuf);
  gate2_kernel<<<N_TOK / 32, 256, 0, stream>>>(gbuf, Wg2, bg2, top_idx, top_w, counts);
  g3_kernel<<<1, 64, 0, stream>>>(counts, cursors, off_pad, ntiles, tile_meta, out_tail);
  init_rows_kernel<<<MAXROWS / 256, 256, 0, stream>>>(slot_token, slot_w);
  scatter_kernel<<<N_TOK / 256, 256, 0, stream>>>(top_idx, top_w, off_pad, cursors,
                                                  slot_token, slot_w);

  moe_gemm_kernel<<<dim3(H_DIM / 128, MAXTILES), 256, 0, stream>>>(
      x_bf, D_IN, 1, W1t, b1, D_IN, H_DIM, tile_meta, ntiles, slot_token, slot_w,
      h1, nullptr, 0);
  moe_gemm_kernel<<<dim3(H_DIM / 128, MAXTILES), 256, 0, stream>>>(
      h1, H_DIM, 0, W2t, b2, H_DIM, H_DIM, tile_meta, ntiles, slot_token, slot_w,
      h2, nullptr, 0);
  moe_gemm_kernel<<<dim3(O_DIM / 128, MAXTILES), 256, 0, stream>>>(
      h2, H_DIM, 0, W3t, b3, H_DIM, O_DIM, tile_meta, ntiles, slot_token, slot_w,
      nullptr, out, 1);
}

// Round 4
// 1095.064 us; speedup vs baseline: 1.0482x; 1.0482x over previous
//
#include <hip/hip_runtime.h>
#include <hip/hip_bf16.h>
#include <cstdint>
#include <cstddef>

// MoE: N=8192 tokens, D=1024, H=2048, O=1024, E=8 experts, G=256 gate hidden, K=2
// R3: identical to R2 submission (R2 failed on container acquisition, not kernel).
#define N_TOK 8192
#define D_IN  1024
#define H_DIM 2048
#define O_DIM 1024
#define E_NUM 8
#define G_DIM 256
#define MAXTILES 136            // ceil(16384/128) + 8 experts padding worst case
#define MAXROWS  (MAXTILES*128) // 17408

typedef __attribute__((ext_vector_type(8))) __bf16 bf16x8;
typedef __attribute__((ext_vector_type(4))) __bf16 bf16x4;
typedef __attribute__((ext_vector_type(4))) float floatx4;

#define GCAST(p) ((__attribute__((address_space(1))) void*)(void*)(p))
#define LCAST(p) ((__attribute__((address_space(3))) void*)(p))

// ---------------- cast x (fp32 -> bf16) ----------------
__global__ __launch_bounds__(256) void cast_x_kernel(const float* __restrict__ x,
                                                     __bf16* __restrict__ xb) {
  int i = (blockIdx.x * 256 + threadIdx.x) * 4;
  float4 v = *reinterpret_cast<const float4*>(x + i);
  bf16x4 o;
  o.x = (__bf16)v.x; o.y = (__bf16)v.y; o.z = (__bf16)v.z; o.w = (__bf16)v.w;
  *reinterpret_cast<bf16x4*>(xb + i) = o;
}

// ---------------- transpose+cast weights: W[e][k][n] fp32 -> Wt[e][n][k] bf16 ----------------
// 64x64 tile, float4 loads, bf16x8 (16B) stores.
__global__ __launch_bounds__(256) void transpose_w_kernel(const float* __restrict__ src,
                                                          __bf16* __restrict__ dst,
                                                          int K, int N) {
  __shared__ float tl[64][68];
  int e = blockIdx.z;
  const float* s = src + (size_t)e * K * N;
  __bf16* d = dst + (size_t)e * K * N;
  int k0 = blockIdx.y * 64, n0 = blockIdx.x * 64;
  int t = threadIdx.x;
  int kr = t >> 4, nc = t & 15;
#pragma unroll
  for (int p = 0; p < 4; p++) {
    float4 v = *reinterpret_cast<const float4*>(
        s + (size_t)(k0 + kr + p * 16) * N + n0 + nc * 4);
    *reinterpret_cast<float4*>(&tl[kr + p * 16][nc * 4]) = v;
  }
  __syncthreads();
  int n = t >> 2, kg = t & 3;
#pragma unroll
  for (int p = 0; p < 2; p++) {
    bf16x8 o;
#pragma unroll
    for (int j = 0; j < 8; j++) o[j] = (__bf16)tl[p * 32 + kg * 8 + j][n];
    *reinterpret_cast<bf16x8*>(d + (size_t)(n0 + n) * K + k0 + p * 32 + kg * 8) = o;
  }
}

// ---------------- gate layer 1 (fp32 GEMM 8192x256x1024 + bias + relu) ----------------
__global__ __launch_bounds__(256) void gate1_kernel(const float* __restrict__ x,
                                                    const float* __restrict__ Wg1,
                                                    const float* __restrict__ bg1,
                                                    float* __restrict__ g) {
  __shared__ float As[32][68];
  __shared__ float Bs[32][68];
  int bn = blockIdx.x, bm = blockIdx.y;
  int t = threadIdx.x;
  int tm = t >> 4, tn = t & 15;
  float acc[4][4] = {};
  for (int k0 = 0; k0 < D_IN; k0 += 32) {
#pragma unroll
    for (int i = 0; i < 2; i++) {
      int idx = t + 256 * i;
      int row = idx >> 3, c4 = idx & 7;
      float4 v = *reinterpret_cast<const float4*>(
          x + (size_t)(bm * 64 + row) * D_IN + k0 + c4 * 4);
      As[c4 * 4 + 0][row] = v.x;
      As[c4 * 4 + 1][row] = v.y;
      As[c4 * 4 + 2][row] = v.z;
      As[c4 * 4 + 3][row] = v.w;
      int brow = idx >> 4, bc4 = idx & 15;
      float4 wv = *reinterpret_cast<const float4*>(
          Wg1 + (size_t)(k0 + brow) * G_DIM + bn * 64 + bc4 * 4);
      *reinterpret_cast<float4*>(&Bs[brow][bc4 * 4]) = wv;
    }
    __syncthreads();
#pragma unroll
    for (int k = 0; k < 32; k++) {
      float4 av = *reinterpret_cast<const float4*>(&As[k][tm * 4]);
      float4 bv = *reinterpret_cast<const float4*>(&Bs[k][tn * 4]);
      float a4[4] = {av.x, av.y, av.z, av.w};
      float b4[4] = {bv.x, bv.y, bv.z, bv.w};
#pragma unroll
      for (int r = 0; r < 4; r++)
#pragma unroll
        for (int c = 0; c < 4; c++) acc[r][c] = fmaf(a4[r], b4[c], acc[r][c]);
    }
    __syncthreads();
  }
  int gr = bm * 64 + tm * 4, gc = bn * 64 + tn * 4;
#pragma unroll
  for (int r = 0; r < 4; r++) {
    float4 o;
    o.x = fmaxf(acc[r][0] + bg1[gc + 0], 0.f);
    o.y = fmaxf(acc[r][1] + bg1[gc + 1], 0.f);
    o.z = fmaxf(acc[r][2] + bg1[gc + 2], 0.f);
    o.w = fmaxf(acc[r][3] + bg1[gc + 3], 0.f);
    *reinterpret_cast<float4*>(g + (size_t)(gr + r) * G_DIM + gc) = o;
  }
}

// ---------------- gate layer 2 + softmax/top2/renorm ----------------
__global__ __launch_bounds__(256) void gate2_kernel(const float* __restrict__ g,
                                                    const float* __restrict__ Wg2,
                                                    const float* __restrict__ bg2,
                                                    int* __restrict__ top_idx,
                                                    float* __restrict__ top_w,
                                                    int* __restrict__ counts) {
  __shared__ float lg[32][9];
  int t = threadIdx.x;
  int tl = t >> 3, e = t & 7;
  int n = blockIdx.x * 32 + tl;
  const float* gr = g + (size_t)n * G_DIM;
  float acc = bg2[e];
  for (int i = 0; i < G_DIM; i += 4) {
    float4 v = *reinterpret_cast<const float4*>(gr + i);
    acc += v.x * Wg2[(i + 0) * E_NUM + e];
    acc += v.y * Wg2[(i + 1) * E_NUM + e];
    acc += v.z * Wg2[(i + 2) * E_NUM + e];
    acc += v.w * Wg2[(i + 3) * E_NUM + e];
  }
  lg[tl][e] = acc;
  __syncthreads();
  if (e == 0) {
    float l[8];
#pragma unroll
    for (int i = 0; i < 8; i++) l[i] = lg[tl][i];
    int i0 = 0;
    for (int i = 1; i < 8; i++)
      if (l[i] > l[i0]) i0 = i;           // first-occurrence max (matches top_k tiebreak)
    int i1 = (i0 == 0) ? 1 : 0;
    for (int i = 0; i < 8; i++)
      if (i != i0 && l[i] > l[i1]) i1 = i;
    float d = expf(l[i1] - l[i0]);
    float w0 = 1.f / (1.f + d);
    float w1 = d * w0;
    top_idx[n * 2 + 0] = i0;
    top_idx[n * 2 + 1] = i1;
    top_w[n * 2 + 0] = w0;
    top_w[n * 2 + 1] = w1;
    atomicAdd(&counts[i0], 1);
    atomicAdd(&counts[i1], 1);
  }
}

// ---------------- prefix/tiles/aux-loss + pad-slot init (single block) ----------------
__global__ void g3_kernel(const int* __restrict__ counts, int* __restrict__ cursors,
                          int* __restrict__ off_pad, int* __restrict__ ntiles,
                          int* __restrict__ tile_meta, float* __restrict__ out_tail,
                          int* __restrict__ slot_token, float* __restrict__ slot_w) {
  if (threadIdx.x == 0) {
    int off = 0, nt = 0;
    float mse = 0.f;
    for (int e = 0; e < E_NUM; e++) {
      off_pad[e] = off;
      int c = counts[e];
      int tiles = (c + 127) >> 7;
      for (int i = 0; i < tiles; i++) {
        tile_meta[nt * 2 + 0] = e;
        tile_meta[nt * 2 + 1] = off + i * 128;
        nt++;
      }
      off += tiles << 7;
      cursors[e] = 0;
      float u = (float)c / (float)N_TOK;
      out_tail[1 + e] = u;
      float dd = u - 0.125f;
      mse += dd * dd;
    }
    *ntiles = nt;
    out_tail[0] = (mse / 8.0f) * 0.01f; // balance_loss
  }
  // all threads: init every slot to (token 0, weight 0); scatter overwrites used ones
  for (int s = threadIdx.x; s < MAXROWS; s += 256) {
    slot_token[s] = 0;
    slot_w[s] = 0.f;
  }
}

// ---------------- scatter tokens into per-expert segments ----------------
__global__ __launch_bounds__(256) void scatter_kernel(const int* __restrict__ top_idx,
                                                      const float* __restrict__ top_w,
                                                      const int* __restrict__ off_pad,
                                                      int* __restrict__ cursors,
                                                      int* __restrict__ slot_token,
                                                      float* __restrict__ slot_w) {
  int n = blockIdx.x * 256 + threadIdx.x;
#pragma unroll
  for (int k = 0; k < 2; k++) {
    int e = top_idx[n * 2 + k];
    int pos = atomicAdd(&cursors[e], 1);
    int s = off_pad[e] + pos;
    slot_token[s] = n;
    slot_w[s] = top_w[n * 2 + k];
  }
}

// ---------------- expert GEMM: 128x128 tile, bf16 MFMA 16x16x32, global_load_lds staging ----------------
// LDS bank-conflict fix: chunk (row, kch) stored at slot kch ^ ((row>>1)&3).
// Staging lanes fetch permuted 16B chunks of the same 64B segment (coalescing kept);
// fragment reads at lq ^ ((row>>1)&3) hit each bank-quad exactly 2-way (free, m136).
__global__ __launch_bounds__(256) void moe_gemm_kernel(
    const __bf16* __restrict__ A, int Astride, int gatherA,
    const __bf16* __restrict__ Wt, const float* __restrict__ bias,
    int Kdim, int Ndim,
    const int* __restrict__ tile_meta, const int* __restrict__ ntiles_p,
    const int* __restrict__ slot_token, const float* __restrict__ slot_w,
    __bf16* __restrict__ h_out, float* __restrict__ out_final, int finalMode) {
  int tile = blockIdx.y;
  if (tile >= *ntiles_p) return;
  __shared__ __bf16 As[128 * 32];
  __shared__ __bf16 Bs[128 * 32];
  int ex = tile_meta[tile * 2 + 0];
  int slot0 = tile_meta[tile * 2 + 1];
  int n0 = blockIdx.x * 128;
  int t = threadIdx.x, l = t & 63, w = t >> 6;

  // staging address setup with XOR swizzle
  size_t aoff[2], boff[2];
#pragma unroll
  for (int i = 0; i < 2; i++) {
    int gidx = (w * 2 + i) * 64 + l;
    int row = gidx >> 2;
    int kch = (gidx & 3) ^ ((row >> 1) & 3);
    int sl = slot0 + row;
    long long rb = gatherA ? (long long)slot_token[sl] * Astride
                           : (long long)sl * Astride;
    aoff[i] = (size_t)rb + kch * 8;
    boff[i] = ((size_t)ex * Ndim + n0 + row) * (size_t)Kdim + kch * 8;
  }

  int wm = (w >> 1) * 64, wn = (w & 1) * 64;
  int lm = l & 15, lq = l >> 4;
  floatx4 acc[4][4] = {};

  for (int k0 = 0; k0 < Kdim; k0 += 32) {
#pragma unroll
    for (int i = 0; i < 2; i++) {
      __builtin_amdgcn_global_load_lds(GCAST(A + aoff[i] + k0),
                                       LCAST((char*)As + w * 2048 + i * 1024),
                                       16, 0, 0);
      __builtin_amdgcn_global_load_lds(GCAST(Wt + boff[i] + k0),
                                       LCAST((char*)Bs + w * 2048 + i * 1024),
                                       16, 0, 0);
    }
    __syncthreads();
    bf16x8 af[4], bfr[4];
#pragma unroll
    for (int i = 0; i < 4; i++) {
      int r = wm + i * 16 + lm;
      int s = lq ^ ((r >> 1) & 3);
      af[i] = *reinterpret_cast<const bf16x8*>(As + r * 32 + s * 8);
    }
#pragma unroll
    for (int j = 0; j < 4; j++) {
      int r = wn + j * 16 + lm;
      int s = lq ^ ((r >> 1) & 3);
      bfr[j] = *reinterpret_cast<const bf16x8*>(Bs + r * 32 + s * 8);
    }
#pragma unroll
    for (int i = 0; i < 4; i++)
#pragma unroll
      for (int j = 0; j < 4; j++)
        acc[i][j] = __builtin_amdgcn_mfma_f32_16x16x32_bf16(af[i], bfr[j], acc[i][j], 0, 0, 0);
    __syncthreads();
  }

  // epilogue: C/D layout col=lane&15, row=(lane>>4)*4+reg  [m89-verified]
  float bcol[4];
#pragma unroll
  for (int j = 0; j < 4; j++) bcol[j] = bias[(size_t)ex * Ndim + n0 + wn + j * 16 + lm];

  if (finalMode) {
#pragma unroll
    for (int i = 0; i < 4; i++) {
#pragma unroll
      for (int r = 0; r < 4; r++) {
        int sl = slot0 + wm + i * 16 + lq * 4 + r;
        int tok = slot_token[sl];
        float wgt = slot_w[sl];
        if (wgt != 0.f) {  // padded rows: skip ~1M same-address atomics of 0.0
          float* orow = out_final + (size_t)tok * Ndim + n0 + wn + lm;
#pragma unroll
          for (int j = 0; j < 4; j++) {
            float v = acc[i][j][r] + bcol[j];
            atomicAdd(orow + j * 16, wgt * v);
          }
        }
      }
    }
  } else {
#pragma unroll
    for (int i = 0; i < 4; i++) {
#pragma unroll
      for (int r = 0; r < 4; r++) {
        int sl = slot0 + wm + i * 16 + lq * 4 + r;
        __bf16* hrow = h_out + (size_t)sl * Ndim + n0 + wn + lm;
#pragma unroll
        for (int j = 0; j < 4; j++) {
          float v = fmaxf(acc[i][j][r] + bcol[j], 0.f);
          hrow[j * 16] = (__bf16)v;
        }
      }
    }
  }
}

// ---------------- launch ----------------
extern "C" void kernel_launch(void* const* d_in, const int* in_sizes, int n_in,
                              void* d_out, int out_size, void* d_ws, size_t ws_size,
                              hipStream_t stream) {
  const float* x   = (const float*)d_in[0];
  const float* Wg1 = (const float*)d_in[1];
  const float* bg1 = (const float*)d_in[2];
  const float* Wg2 = (const float*)d_in[3];
  const float* bg2 = (const float*)d_in[4];
  const float* W1  = (const float*)d_in[5];
  const float* b1  = (const float*)d_in[6];
  const float* W2  = (const float*)d_in[7];
  const float* b2  = (const float*)d_in[8];
  const float* W3  = (const float*)d_in[9];
  const float* b3  = (const float*)d_in[10];
  float* out = (float*)d_out;

  char* ws = (char*)d_ws;
  __bf16* x_bf       = (__bf16*)(ws + 0);          // 16,777,216
  __bf16* W1t        = (__bf16*)(ws + 16777216);   // 33,554,432
  __bf16* W2t        = (__bf16*)(ws + 50331648);   // 67,108,864
  __bf16* W3t        = (__bf16*)(ws + 117440512);  // 33,554,432
  __bf16* h1         = (__bf16*)(ws + 150994944);  // 71,303,168
  __bf16* h2         = (__bf16*)(ws + 222298112);  // 71,303,168
  float*  gbuf       = (float*) (ws + 293601280);  // 8,388,608
  int*    top_idx    = (int*)   (ws + 301989888);  // 65,536
  float*  top_w      = (float*) (ws + 302055424);  // 65,536
  int*    slot_token = (int*)   (ws + 302120960);  // 69,632
  float*  slot_w     = (float*) (ws + 302190592);  // 69,632
  int*    meta       = (int*)   (ws + 302260224);
  int* counts    = meta;       // 8
  int* cursors   = meta + 8;   // 8
  int* off_pad   = meta + 16;  // 8
  int* ntiles    = meta + 24;  // 1
  int* tile_meta = meta + 32;  // 272
  float* out_tail = out + (size_t)N_TOK * O_DIM;   // [balance_loss, usage x8]

  hipMemsetAsync(d_out, 0, ((size_t)N_TOK * O_DIM + 9) * sizeof(float), stream);
  hipMemsetAsync(meta, 0, 64, stream); // zero counts+cursors

  cast_x_kernel<<<(N_TOK * D_IN) / 1024, 256, 0, stream>>>(x, x_bf);
  transpose_w_kernel<<<dim3(H_DIM / 64, D_IN / 64, E_NUM), 256, 0, stream>>>(W1, W1t, D_IN, H_DIM);
  transpose_w_kernel<<<dim3(H_DIM / 64, H_DIM / 64, E_NUM), 256, 0, stream>>>(W2, W2t, H_DIM, H_DIM);
  transpose_w_kernel<<<dim3(O_DIM / 64, H_DIM / 64, E_NUM), 256, 0, stream>>>(W3, W3t, H_DIM, O_DIM);

  gate1_kernel<<<dim3(G_DIM / 64, N_TOK / 64), 256, 0, stream>>>(x, Wg1, bg1, gbuf);
  gate2_kernel<<<N_TOK / 32, 256, 0, stream>>>(gbuf, Wg2, bg2, top_idx, top_w, counts);
  g3_kernel<<<1, 256, 0, stream>>>(counts, cursors, off_pad, ntiles, tile_meta, out_tail,
                                   slot_token, slot_w);
  scatter_kernel<<<N_TOK / 256, 256, 0, stream>>>(top_idx, top_w, off_pad, cursors,
                                                  slot_token, slot_w);

  moe_gemm_kernel<<<dim3(H_DIM / 128, MAXTILES), 256, 0, stream>>>(
      x_bf, D_IN, 1, W1t, b1, D_IN, H_DIM, tile_meta, ntiles, slot_token, slot_w,
      h1, nullptr, 0);
  moe_gemm_kernel<<<dim3(H_DIM / 128, MAXTILES), 256, 0, stream>>>(
      h1, H_DIM, 0, W2t, b2, H_DIM, H_DIM, tile_meta, ntiles, slot_token, slot_w,
      h2, nullptr, 0);
  moe_gemm_kernel<<<dim3(O_DIM / 128, MAXTILES), 256, 0, stream>>>(
      h2, H_DIM, 0, W3t, b3, H_DIM, O_DIM, tile_meta, ntiles, slot_token, slot_w,
      nullptr, out, 1);
}

// Round 5
// 1051.209 us; speedup vs baseline: 1.0920x; 1.0417x over previous
//
#include <hip/hip_runtime.h>
#include <hip/hip_bf16.h>
#include <cstdint>
#include <cstddef>

// MoE: N=8192 tokens, D=1024, H=2048, O=1024, E=8 experts, G=256 gate hidden, K=2
#define N_TOK 8192
#define D_IN  1024
#define H_DIM 2048
#define O_DIM 1024
#define E_NUM 8
#define G_DIM 256
#define MAXTILES 136            // ceil(16384/128) + 8 experts padding worst case
#define MAXROWS  (MAXTILES*128) // 17408

typedef __attribute__((ext_vector_type(8))) __bf16 bf16x8;
typedef __attribute__((ext_vector_type(4))) __bf16 bf16x4;
typedef __attribute__((ext_vector_type(4))) float floatx4;

#define GCAST(p) ((__attribute__((address_space(1))) void*)(void*)(p))
#define LCAST(p) ((__attribute__((address_space(3))) void*)(p))

// ---- fused prep kernel: gate1 (512) | cast_x (4096) | trW1 (4096) | trW2 (8192) | trW3 (4096)
// gate1 blocks FIRST so the VALU-bound job starts immediately and overlaps the
// HBM-bound transpose/cast blocks across CUs (one launch instead of 5 serial).
#define JOB_G1_END   512
#define JOB_CAST_END 4608
#define JOB_W1_END   8704
#define JOB_W2_END   16896
#define JOB_W3_END   20992

__device__ inline void transpose_body(const float* __restrict__ src,
                                      __bf16* __restrict__ dst,
                                      int K, int N, int e, int ktile, int ntile,
                                      float* smemf) {
  float (*tl)[68] = (float(*)[68])smemf;  // 64 x 68 floats = 17408 B
  const float* s = src + (size_t)e * K * N;
  __bf16* d = dst + (size_t)e * K * N;
  int k0 = ktile * 64, n0 = ntile * 64;
  int t = threadIdx.x;
  int kr = t >> 4, nc = t & 15;
#pragma unroll
  for (int p = 0; p < 4; p++) {
    float4 v = *reinterpret_cast<const float4*>(
        s + (size_t)(k0 + kr + p * 16) * N + n0 + nc * 4);
    *reinterpret_cast<float4*>(&tl[kr + p * 16][nc * 4]) = v;
  }
  __syncthreads();
  int n = t >> 2, kg = t & 3;
#pragma unroll
  for (int p = 0; p < 2; p++) {
    bf16x8 o;
#pragma unroll
    for (int j = 0; j < 8; j++) o[j] = (__bf16)tl[p * 32 + kg * 8 + j][n];
    *reinterpret_cast<bf16x8*>(d + (size_t)(n0 + n) * K + k0 + p * 32 + kg * 8) = o;
  }
}

__device__ inline void gate1_body(const float* __restrict__ x,
                                  const float* __restrict__ Wg1,
                                  const float* __restrict__ bg1,
                                  float* __restrict__ g,
                                  int bn, int bm, float* smemf) {
  float (*As)[68] = (float(*)[68])smemf;            // 32 x 68
  float (*Bs)[68] = (float(*)[68])(smemf + 32 * 68);
  int t = threadIdx.x;
  int tm = t >> 4, tn = t & 15;
  float acc[4][4] = {};
  for (int k0 = 0; k0 < D_IN; k0 += 32) {
#pragma unroll
    for (int i = 0; i < 2; i++) {
      int idx = t + 256 * i;
      int row = idx >> 3, c4 = idx & 7;
      float4 v = *reinterpret_cast<const float4*>(
          x + (size_t)(bm * 64 + row) * D_IN + k0 + c4 * 4);
      As[c4 * 4 + 0][row] = v.x;
      As[c4 * 4 + 1][row] = v.y;
      As[c4 * 4 + 2][row] = v.z;
      As[c4 * 4 + 3][row] = v.w;
      int brow = idx >> 4, bc4 = idx & 15;
      float4 wv = *reinterpret_cast<const float4*>(
          Wg1 + (size_t)(k0 + brow) * G_DIM + bn * 64 + bc4 * 4);
      *reinterpret_cast<float4*>(&Bs[brow][bc4 * 4]) = wv;
    }
    __syncthreads();
#pragma unroll
    for (int k = 0; k < 32; k++) {
      float4 av = *reinterpret_cast<const float4*>(&As[k][tm * 4]);
      float4 bv = *reinterpret_cast<const float4*>(&Bs[k][tn * 4]);
      float a4[4] = {av.x, av.y, av.z, av.w};
      float b4[4] = {bv.x, bv.y, bv.z, bv.w};
#pragma unroll
      for (int r = 0; r < 4; r++)
#pragma unroll
        for (int c = 0; c < 4; c++) acc[r][c] = fmaf(a4[r], b4[c], acc[r][c]);
    }
    __syncthreads();
  }
  int gr = bm * 64 + tm * 4, gc = bn * 64 + tn * 4;
#pragma unroll
  for (int r = 0; r < 4; r++) {
    float4 o;
    o.x = fmaxf(acc[r][0] + bg1[gc + 0], 0.f);
    o.y = fmaxf(acc[r][1] + bg1[gc + 1], 0.f);
    o.z = fmaxf(acc[r][2] + bg1[gc + 2], 0.f);
    o.w = fmaxf(acc[r][3] + bg1[gc + 3], 0.f);
    *reinterpret_cast<float4*>(g + (size_t)(gr + r) * G_DIM + gc) = o;
  }
}

__global__ __launch_bounds__(256) void prep_kernel(
    const float* __restrict__ x, __bf16* __restrict__ xb,
    const float* __restrict__ W1, __bf16* __restrict__ W1t,
    const float* __restrict__ W2, __bf16* __restrict__ W2t,
    const float* __restrict__ W3, __bf16* __restrict__ W3t,
    const float* __restrict__ Wg1, const float* __restrict__ bg1,
    float* __restrict__ g) {
  __shared__ float smemf[4352];  // 17408 B, unioned across jobs
  int b = blockIdx.x;
  if (b < JOB_G1_END) {
    gate1_body(x, Wg1, bg1, g, b & 3, b >> 2, smemf);
  } else if (b < JOB_CAST_END) {
    int id = b - JOB_G1_END;
    int i = id * 2048 + threadIdx.x * 8;
    float4 v0 = *reinterpret_cast<const float4*>(x + i);
    float4 v1 = *reinterpret_cast<const float4*>(x + i + 4);
    bf16x8 o;
    o[0] = (__bf16)v0.x; o[1] = (__bf16)v0.y; o[2] = (__bf16)v0.z; o[3] = (__bf16)v0.w;
    o[4] = (__bf16)v1.x; o[5] = (__bf16)v1.y; o[6] = (__bf16)v1.z; o[7] = (__bf16)v1.w;
    *reinterpret_cast<bf16x8*>(xb + i) = o;
  } else if (b < JOB_W1_END) {
    int id = b - JOB_CAST_END;  // 32 n x 16 k x 8 e
    transpose_body(W1, W1t, D_IN, H_DIM, id >> 9, (id >> 5) & 15, id & 31, smemf);
  } else if (b < JOB_W2_END) {
    int id = b - JOB_W1_END;    // 32 n x 32 k x 8 e
    transpose_body(W2, W2t, H_DIM, H_DIM, id >> 10, (id >> 5) & 31, id & 31, smemf);
  } else {
    int id = b - JOB_W2_END;    // 16 n x 32 k x 8 e
    transpose_body(W3, W3t, H_DIM, O_DIM, id >> 9, (id >> 4) & 31, id & 15, smemf);
  }
}

// ---------------- gate layer 2 + softmax/top2/renorm ----------------
__global__ __launch_bounds__(256) void gate2_kernel(const float* __restrict__ g,
                                                    const float* __restrict__ Wg2,
                                                    const float* __restrict__ bg2,
                                                    int* __restrict__ top_idx,
                                                    float* __restrict__ top_w,
                                                    int* __restrict__ counts) {
  __shared__ float lg[32][9];
  int t = threadIdx.x;
  int tl = t >> 3, e = t & 7;
  int n = blockIdx.x * 32 + tl;
  const float* gr = g + (size_t)n * G_DIM;
  float acc = bg2[e];
  for (int i = 0; i < G_DIM; i += 4) {
    float4 v = *reinterpret_cast<const float4*>(gr + i);
    acc += v.x * Wg2[(i + 0) * E_NUM + e];
    acc += v.y * Wg2[(i + 1) * E_NUM + e];
    acc += v.z * Wg2[(i + 2) * E_NUM + e];
    acc += v.w * Wg2[(i + 3) * E_NUM + e];
  }
  lg[tl][e] = acc;
  __syncthreads();
  if (e == 0) {
    float l[8];
#pragma unroll
    for (int i = 0; i < 8; i++) l[i] = lg[tl][i];
    int i0 = 0;
    for (int i = 1; i < 8; i++)
      if (l[i] > l[i0]) i0 = i;           // first-occurrence max (matches top_k tiebreak)
    int i1 = (i0 == 0) ? 1 : 0;
    for (int i = 0; i < 8; i++)
      if (i != i0 && l[i] > l[i1]) i1 = i;
    float d = expf(l[i1] - l[i0]);
    float w0 = 1.f / (1.f + d);
    float w1 = d * w0;
    top_idx[n * 2 + 0] = i0;
    top_idx[n * 2 + 1] = i1;
    top_w[n * 2 + 0] = w0;
    top_w[n * 2 + 1] = w1;
    atomicAdd(&counts[i0], 1);
    atomicAdd(&counts[i1], 1);
  }
}

// ---------------- prefix/tiles/aux-loss + pad-slot init (single block) ----------------
__global__ void g3_kernel(const int* __restrict__ counts, int* __restrict__ cursors,
                          int* __restrict__ off_pad, int* __restrict__ ntiles,
                          int* __restrict__ tile_meta, float* __restrict__ out_tail,
                          int* __restrict__ slot_token) {
  if (threadIdx.x == 0) {
    int off = 0, nt = 0;
    float mse = 0.f;
    for (int e = 0; e < E_NUM; e++) {
      off_pad[e] = off;
      int c = counts[e];
      int tiles = (c + 127) >> 7;
      for (int i = 0; i < tiles; i++) {
        tile_meta[nt * 2 + 0] = e;
        tile_meta[nt * 2 + 1] = off + i * 128;
        nt++;
      }
      off += tiles << 7;
      cursors[e] = 0;
      float u = (float)c / (float)N_TOK;
      out_tail[1 + e] = u;
      float dd = u - 0.125f;
      mse += dd * dd;
    }
    *ntiles = nt;
    out_tail[0] = (mse / 8.0f) * 0.01f; // balance_loss
  }
  // pad slots gather token 0 (harmless; their y rows are never combined)
  for (int s = threadIdx.x; s < MAXROWS; s += 256) slot_token[s] = 0;
}

// ---------------- scatter tokens into per-expert segments ----------------
__global__ __launch_bounds__(256) void scatter_kernel(const int* __restrict__ top_idx,
                                                      const int* __restrict__ off_pad,
                                                      int* __restrict__ cursors,
                                                      int* __restrict__ slot_token,
                                                      int* __restrict__ token_slots) {
  int n = blockIdx.x * 256 + threadIdx.x;
#pragma unroll
  for (int k = 0; k < 2; k++) {
    int e = top_idx[n * 2 + k];
    int pos = atomicAdd(&cursors[e], 1);
    int s = off_pad[e] + pos;
    slot_token[s] = n;
    token_slots[n * 2 + k] = s;
  }
}

// ---------------- expert GEMM: 128x128 tile, bf16 MFMA 16x16x32, global_load_lds staging ----------------
// LDS bank-conflict fix (verified R4: SQ_LDS_BANK_CONFLICT 1.73e7 -> 0):
// chunk (row, kch) stored at slot kch ^ ((row>>1)&3); reads are 2-way (free, m136).
// mode 0: h_out = relu(acc+bias) bf16;  mode 1: y_out[slot] = acc+bias fp32 (plain stores)
__global__ __launch_bounds__(256) void moe_gemm_kernel(
    const __bf16* __restrict__ A, int Astride, int gatherA,
    const __bf16* __restrict__ Wt, const float* __restrict__ bias,
    int Kdim, int Ndim,
    const int* __restrict__ tile_meta, const int* __restrict__ ntiles_p,
    const int* __restrict__ slot_token,
    __bf16* __restrict__ h_out, float* __restrict__ y_out, int finalMode) {
  int tile = blockIdx.y;
  if (tile >= *ntiles_p) return;
  __shared__ __bf16 As[128 * 32];
  __shared__ __bf16 Bs[128 * 32];
  int ex = tile_meta[tile * 2 + 0];
  int slot0 = tile_meta[tile * 2 + 1];
  int n0 = blockIdx.x * 128;
  int t = threadIdx.x, l = t & 63, w = t >> 6;

  size_t aoff[2], boff[2];
#pragma unroll
  for (int i = 0; i < 2; i++) {
    int gidx = (w * 2 + i) * 64 + l;
    int row = gidx >> 2;
    int kch = (gidx & 3) ^ ((row >> 1) & 3);
    int sl = slot0 + row;
    long long rb = gatherA ? (long long)slot_token[sl] * Astride
                           : (long long)sl * Astride;
    aoff[i] = (size_t)rb + kch * 8;
    boff[i] = ((size_t)ex * Ndim + n0 + row) * (size_t)Kdim + kch * 8;
  }

  int wm = (w >> 1) * 64, wn = (w & 1) * 64;
  int lm = l & 15, lq = l >> 4;
  floatx4 acc[4][4] = {};

  for (int k0 = 0; k0 < Kdim; k0 += 32) {
#pragma unroll
    for (int i = 0; i < 2; i++) {
      __builtin_amdgcn_global_load_lds(GCAST(A + aoff[i] + k0),
                                       LCAST((char*)As + w * 2048 + i * 1024),
                                       16, 0, 0);
      __builtin_amdgcn_global_load_lds(GCAST(Wt + boff[i] + k0),
                                       LCAST((char*)Bs + w * 2048 + i * 1024),
                                       16, 0, 0);
    }
    __syncthreads();
    bf16x8 af[4], bfr[4];
#pragma unroll
    for (int i = 0; i < 4; i++) {
      int r = wm + i * 16 + lm;
      int s = lq ^ ((r >> 1) & 3);
      af[i] = *reinterpret_cast<const bf16x8*>(As + r * 32 + s * 8);
    }
#pragma unroll
    for (int j = 0; j < 4; j++) {
      int r = wn + j * 16 + lm;
      int s = lq ^ ((r >> 1) & 3);
      bfr[j] = *reinterpret_cast<const bf16x8*>(Bs + r * 32 + s * 8);
    }
#pragma unroll
    for (int i = 0; i < 4; i++)
#pragma unroll
      for (int j = 0; j < 4; j++)
        acc[i][j] = __builtin_amdgcn_mfma_f32_16x16x32_bf16(af[i], bfr[j], acc[i][j], 0, 0, 0);
    __syncthreads();
  }

  // epilogue: C/D layout col=lane&15, row=(lane>>4)*4+reg  [m89-verified]
  float bcol[4];
#pragma unroll
  for (int j = 0; j < 4; j++) bcol[j] = bias[(size_t)ex * Ndim + n0 + wn + j * 16 + lm];

  if (finalMode) {
#pragma unroll
    for (int i = 0; i < 4; i++) {
#pragma unroll
      for (int r = 0; r < 4; r++) {
        int sl = slot0 + wm + i * 16 + lq * 4 + r;
        float* yrow = y_out + (size_t)sl * Ndim + n0 + wn + lm;
#pragma unroll
        for (int j = 0; j < 4; j++) yrow[j * 16] = acc[i][j][r] + bcol[j];
      }
    }
  } else {
#pragma unroll
    for (int i = 0; i < 4; i++) {
#pragma unroll
      for (int r = 0; r < 4; r++) {
        int sl = slot0 + wm + i * 16 + lq * 4 + r;
        __bf16* hrow = h_out + (size_t)sl * Ndim + n0 + wn + lm;
#pragma unroll
        for (int j = 0; j < 4; j++) {
          float v = fmaxf(acc[i][j][r] + bcol[j], 0.f);
          hrow[j * 16] = (__bf16)v;
        }
      }
    }
  }
}

// ---------------- combine: out[n] = w0*y[s0] + w1*y[s1] (exact fp32, no atomics) ----------------
__global__ __launch_bounds__(256) void combine_kernel(const float* __restrict__ y,
                                                      const int* __restrict__ token_slots,
                                                      const float* __restrict__ top_w,
                                                      float* __restrict__ out) {
  int n = blockIdx.x;
  int t = threadIdx.x;
  int s0 = token_slots[n * 2 + 0], s1 = token_slots[n * 2 + 1];
  float w0 = top_w[n * 2 + 0], w1 = top_w[n * 2 + 1];
  float4 a = reinterpret_cast<const float4*>(y + (size_t)s0 * O_DIM)[t];
  float4 b = reinterpret_cast<const float4*>(y + (size_t)s1 * O_DIM)[t];
  float4 o;
  o.x = w0 * a.x + w1 * b.x;
  o.y = w0 * a.y + w1 * b.y;
  o.z = w0 * a.z + w1 * b.z;
  o.w = w0 * a.w + w1 * b.w;
  reinterpret_cast<float4*>(out + (size_t)n * O_DIM)[t] = o;
}

// ---------------- launch ----------------
extern "C" void kernel_launch(void* const* d_in, const int* in_sizes, int n_in,
                              void* d_out, int out_size, void* d_ws, size_t ws_size,
                              hipStream_t stream) {
  const float* x   = (const float*)d_in[0];
  const float* Wg1 = (const float*)d_in[1];
  const float* bg1 = (const float*)d_in[2];
  const float* Wg2 = (const float*)d_in[3];
  const float* bg2 = (const float*)d_in[4];
  const float* W1  = (const float*)d_in[5];
  const float* b1  = (const float*)d_in[6];
  const float* W2  = (const float*)d_in[7];
  const float* b2  = (const float*)d_in[8];
  const float* W3  = (const float*)d_in[9];
  const float* b3  = (const float*)d_in[10];
  float* out = (float*)d_out;

  char* ws = (char*)d_ws;
  __bf16* x_bf       = (__bf16*)(ws + 0);          // 16,777,216
  __bf16* W1t        = (__bf16*)(ws + 16777216);   // 33,554,432
  __bf16* W2t        = (__bf16*)(ws + 50331648);   // 67,108,864
  __bf16* W3t        = (__bf16*)(ws + 117440512);  // 33,554,432
  __bf16* h1         = (__bf16*)(ws + 150994944);  // 71,303,168
  __bf16* h2         = (__bf16*)(ws + 222298112);  // 71,303,168
  float*  y          = (float*) (ws + 150994944);  // aliases h1 (free after L2 reads it)
  float*  gbuf       = (float*) (ws + 293601280);  // 8,388,608
  int*    top_idx    = (int*)   (ws + 301989888);  // 65,536
  float*  top_w      = (float*) (ws + 302055424);  // 65,536
  int*    slot_token = (int*)   (ws + 302120960);  // 69,632
  int*    token_slots= (int*)   (ws + 302190592);  // 65,536
  int*    meta       = (int*)   (ws + 302260224);
  int* counts    = meta;       // 8
  int* cursors   = meta + 8;   // 8
  int* off_pad   = meta + 16;  // 8
  int* ntiles    = meta + 24;  // 1
  int* tile_meta = meta + 32;  // 272
  float* out_tail = out + (size_t)N_TOK * O_DIM;   // [balance_loss, usage x8]

  hipMemsetAsync(meta, 0, 64, stream); // zero counts+cursors

  prep_kernel<<<JOB_W3_END, 256, 0, stream>>>(x, x_bf, W1, W1t, W2, W2t, W3, W3t,
                                              Wg1, bg1, gbuf);
  gate2_kernel<<<N_TOK / 32, 256, 0, stream>>>(gbuf, Wg2, bg2, top_idx, top_w, counts);
  g3_kernel<<<1, 256, 0, stream>>>(counts, cursors, off_pad, ntiles, tile_meta, out_tail,
                                   slot_token);
  scatter_kernel<<<N_TOK / 256, 256, 0, stream>>>(top_idx, off_pad, cursors,
                                                  slot_token, token_slots);

  moe_gemm_kernel<<<dim3(H_DIM / 128, MAXTILES), 256, 0, stream>>>(
      x_bf, D_IN, 1, W1t, b1, D_IN, H_DIM, tile_meta, ntiles, slot_token,
      h1, nullptr, 0);
  moe_gemm_kernel<<<dim3(H_DIM / 128, MAXTILES), 256, 0, stream>>>(
      h1, H_DIM, 0, W2t, b2, H_DIM, H_DIM, tile_meta, ntiles, slot_token,
      h2, nullptr, 0);
  moe_gemm_kernel<<<dim3(O_DIM / 128, MAXTILES), 256, 0, stream>>>(
      h2, H_DIM, 0, W3t, b3, H_DIM, O_DIM, tile_meta, ntiles, slot_token,
      nullptr, y, 1);
  combine_kernel<<<N_TOK, 256, 0, stream>>>(y, token_slots, top_w, out);
}